// Round 3
// baseline (185.401 us; speedup 1.0000x reference)
//
#include <hip/hip_runtime.h>

// BoTNet attention, MI355X bf16-MFMA, round 10.
//  * raw .view: (b,o,s) row-major == (bh,i,d) row-major -> no relayout.
//  * pos bias folded into K; log2(e) folded into Q scale (exp2 softmax).
//  * S^T trick + pi-permuted K staging: softmaxed accumulators packed to bf16
//    ARE the PV A-fragments. pi: pr = (r&0x23)|((r&0x0C)<<1)|((r&0x10)>>2).
//  * R9: BK=128/buffer, ones-B MFMA row sums, setprio. 78->69us.
//  * R10: cross-sub-tile pipe overlap. R9 counters showed MfmaUtil(45)+
//    VALUBusy(39) ~= 100-idle: zero MFMA/VALU overlap (serial per-tile chain
//    QK->exp2->pack->PV, 2 phase-aligned waves/SIMD). Restructure each
//    128-row buffer as 4 phases: A=QK0 | B=QK1 interleaved with SM0 |
//    C=PV0+ones0 interleaved with SM1 | D=PV1+ones1. In-order waves issue
//    exp2/pack in the matrix-pipe accept gaps -> both pipes busy at once.
// ws: Q | K' | V(->OP0 alias) | V^T (8 MiB each) | l[2][65536] f32 | Wb16.

typedef float  f32x4  __attribute__((ext_vector_type(4)));
typedef __bf16 bf16x8 __attribute__((ext_vector_type(8)));
typedef __bf16 bf16x4 __attribute__((ext_vector_type(4)));

__device__ inline float fast_exp2(float x) {
#if __has_builtin(__builtin_amdgcn_exp2f)
  return __builtin_amdgcn_exp2f(x);
#else
  return exp2f(x);
#endif
}

__device__ inline void glds16(const __bf16* g, __bf16* l) {
  __builtin_amdgcn_global_load_lds(
      (const __attribute__((address_space(1))) void*)g,
      (__attribute__((address_space(3))) void*)l, 16, 0, 0);
}

// ---------------------------------------------------------------------------
// Kernel 0: W f32 -> bf16.
// ---------------------------------------------------------------------------
__global__ __launch_bounds__(256) void w_cvt(
    const float* __restrict__ w, __bf16* __restrict__ wb)
{
  int idx = blockIdx.x * 256 + threadIdx.x;
  f32x4 v = ((const f32x4*)w)[idx];
  bf16x4 o; o[0]=(__bf16)v[0]; o[1]=(__bf16)v[1]; o[2]=(__bf16)v[2]; o[3]=(__bf16)v[3];
  ((bf16x4*)wb)[idx] = o;
}

// ---------------------------------------------------------------------------
// Kernel 1: qkv projection v2 (unchanged).
// ---------------------------------------------------------------------------
__global__ __launch_bounds__(256) void qkv_proj(
    const float* __restrict__ fmap, const __bf16* __restrict__ wb,
    const float* __restrict__ ph,   const float* __restrict__ pw,
    __bf16* __restrict__ Qw, __bf16* __restrict__ Kw, __bf16* __restrict__ Vw)
{
  constexpr int LS = 264;
  __shared__ __bf16 Bs[32 * LS];
  const int tid  = threadIdx.x;
  const int wv   = tid >> 6;
  const int lane = tid & 63;
  const int quad = lane >> 4, l15 = lane & 15;
  const int n0 = blockIdx.x * 32;
  const int b  = blockIdx.y;

#pragma unroll
  for (int i = 0; i < 2; ++i) {
    int id = tid + i * 256;
    int ng = id & 7;
    int kg = id >> 3;
    const float* base = fmap + ((size_t)b * 256 + 4 * kg) * 4096 + n0 + 4 * ng;
    f32x4 v0 = *(const f32x4*)(base);
    f32x4 v1 = *(const f32x4*)(base + 4096);
    f32x4 v2 = *(const f32x4*)(base + 8192);
    f32x4 v3 = *(const f32x4*)(base + 12288);
#pragma unroll
    for (int j = 0; j < 4; ++j) {
      bf16x4 o; o[0]=(__bf16)v0[j]; o[1]=(__bf16)v1[j]; o[2]=(__bf16)v2[j]; o[3]=(__bf16)v3[j];
      *(bf16x4*)(&Bs[(4 * ng + j) * LS + 4 * kg]) = o;
    }
  }
  __syncthreads();

  for (int mt = 0; mt < 12; ++mt) {
    const int region = mt >> 2;
    const int obase  = (mt & 3) * 64;
    const __bf16* aptr = wb + (size_t)(mt * 64 + 16 * wv + l15) * 256 + 8 * quad;

    f32x4 acc[2] = {};
#pragma unroll
    for (int k0 = 0; k0 < 256; k0 += 32) {
      bf16x8 af = *(const bf16x8*)(aptr + k0);
      bf16x8 b0 = *(const bf16x8*)(&Bs[(l15)      * LS + k0 + 8 * quad]);
      bf16x8 b1 = *(const bf16x8*)(&Bs[(16 + l15) * LS + k0 + 8 * quad]);
      acc[0] = __builtin_amdgcn_mfma_f32_16x16x32_bf16(af, b0, acc[0], 0, 0, 0);
      acc[1] = __builtin_amdgcn_mfma_f32_16x16x32_bf16(af, b1, acc[1], 0, 0, 0);
    }

#pragma unroll
    for (int t = 0; t < 2; ++t) {
#pragma unroll
      for (int rr = 0; rr < 4; ++rr) {
        int oreg = obase + 16 * wv + 4 * quad + rr;
        int s    = n0 + 16 * t + l15;
        float val = acc[t][rr];
        size_t off = ((size_t)(b * 256 + oreg)) * 4096 + s;
        if (region == 0) {
          Qw[off] = (__bf16)(val * 0.18033688f);      // 0.125 * log2(e)
        } else if (region == 1) {
          int g = oreg & 63;
          float bias = ph[g * 64 + (s & 63)] + pw[(s >> 6) * 64 + (s & 63)];
          Kw[off] = (__bf16)(val + bias);
        } else {
          Vw[off] = (__bf16)val;
        }
      }
    }
  }
}

// ---------------------------------------------------------------------------
// Kernel 2: V transpose per (b,h): (4096 j x 64 d) -> (64 d x 4096 j)
// ---------------------------------------------------------------------------
__global__ __launch_bounds__(256) void v_transpose(
    const __bf16* __restrict__ Vw, __bf16* __restrict__ Vt)
{
  __shared__ __bf16 T[64 * 72];
  const int tid = threadIdx.x;
  const int j0  = blockIdx.x * 64;
  const int bh  = blockIdx.y;
  const __bf16* src = Vw + (size_t)bh * 262144;
#pragma unroll
  for (int i = 0; i < 2; ++i) {
    int id = tid + i * 256;
    int r = id >> 3, c = (id & 7) * 8;
    *(bf16x8*)(&T[r * 72 + c]) = *(const bf16x8*)(src + (size_t)(j0 + r) * 64 + c);
  }
  __syncthreads();
#pragma unroll
  for (int i = 0; i < 2; ++i) {
    int id = tid + i * 256;
    int d = id >> 3, jc = (id & 7) * 8;
    bf16x8 o;
#pragma unroll
    for (int z = 0; z < 8; ++z) o[z] = T[(jc + z) * 72 + d];
    *(bf16x8*)(Vt + ((size_t)bh * 64 + d) * 4096 + j0 + jc) = o;
  }
}

// ---------------------------------------------------------------------------
// Kernel 3: flash attention v10. m=4 (64 Q-rows/wave, 256/block), BK=128 per
// LDS buffer, 4-phase cross-sub-tile interleave, KV-split over z, 2-stage
// DMA pipeline with double-buffered LDS. grid (16, 16, 2), block 256.
// ---------------------------------------------------------------------------
__global__ __launch_bounds__(256, 2) void flash_attn(
    const __bf16* __restrict__ Qg, const __bf16* __restrict__ Kg,
    const __bf16* __restrict__ Vtg, __bf16* __restrict__ OP0,
    float* __restrict__ lws, float* __restrict__ Og)
{
  __shared__ __bf16 Ks[2 * 128 * 64];     // double-buffered 128-row tiles
  __shared__ __bf16 Vs[2 * 128 * 64];     // (64 KiB total LDS)
  const int tid  = threadIdx.x;
  const int wv   = tid >> 6;
  const int lane = tid & 63;
  const int quad = lane >> 4, l15 = lane & 15;
  const int bh = blockIdx.y;
  const int z  = blockIdx.z;
  const int iw = blockIdx.x * 256 + 64 * wv;
  const int jbase = z * 2048;
  const __bf16* Qb = Qg  + (size_t)bh * 262144;
  const __bf16* Kb = Kg  + (size_t)bh * 262144;
  const __bf16* Vb = Vtg + (size_t)bh * 262144;

  // Q B-frags in registers
  bf16x8 qf[4][2];
#pragma unroll
  for (int m = 0; m < 4; ++m)
#pragma unroll
    for (int c = 0; c < 2; ++c)
      qf[m][c] = *(const bf16x8*)(Qb + (size_t)(iw + 16 * m + l15) * 64 + 32 * c + 8 * quad);

  // DMA staging descriptors (source-side xor swizzle, pi-permuted K rows)
  const int r0  = tid >> 3;
  const int kch = tid & 7;
  const int xc  = (kch ^ (r0 & 7)) * 8;
  const int pr0a = r0, pr1a = r0 + 32;
  const int pr0 = (pr0a & 0x23) | ((pr0a & 0x0C) << 1) | ((pr0a & 0x10) >> 2);
  const int pr1 = (pr1a & 0x23) | ((pr1a & 0x0C) << 1) | ((pr1a & 0x10) >> 2);
  const __bf16* kp0 = Kb + (size_t)(jbase + pr0) * 64 + xc;
  const __bf16* kp1 = Kb + (size_t)(jbase + pr1) * 64 + xc;
  const __bf16* vp0 = Vb + (size_t)r0 * 4096        + jbase + xc;
  const __bf16* vp1 = Vb + (size_t)(r0 + 32) * 4096 + jbase + xc;

  f32x4 acco[4][4] = {};
  f32x4 lacc[4] = {};                     // row sums via ones-B MFMA
  const int swz = (l15 & 7);

  bf16x8 onesb;
#pragma unroll
  for (int r = 0; r < 8; ++r) onesb[r] = (__bf16)1.0f;

  // --- pipeline helpers (buf = 0/1 LDS halves, 8192 elems apart; each buf
  // holds two 64-row sub-tiles 4096 elems apart) ---
  auto dma_tile = [&](int buf) {
    __bf16* k0 = &Ks[buf * 8192 + tid * 8];
    __bf16* v0 = &Vs[buf * 8192 + tid * 8];
    glds16(kp0, k0);         kp0 += 4096;   // sub0: +64 K rows
    glds16(kp1, k0 + 2048);  kp1 += 4096;
    glds16(vp0, v0);         vp0 += 64;     // sub0: +64 V^T cols
    glds16(vp1, v0 + 2048);  vp1 += 64;
    glds16(kp0, k0 + 4096);  kp0 += 4096;   // sub1
    glds16(kp1, k0 + 6144);  kp1 += 4096;
    glds16(vp0, v0 + 4096);  vp0 += 64;
    glds16(vp1, v0 + 6144);  vp1 += 64;
  };

  // 4-phase pair: A=QK0 | B=QK1 (+)SM0 | C=PV0+ones0 (+)SM1 | D=PV1+ones1.
  auto compute_pair = [&](int buf) {
    const __bf16* K0 = &Ks[buf * 8192];
    const __bf16* K1 = K0 + 4096;
    const __bf16* V0 = &Vs[buf * 8192];
    const __bf16* V1 = V0 + 4096;
    f32x4 s0[4][4] = {};
    f32x4 s1[4][4] = {};
    bf16x8 p0[4][2], p1[4][2];

    // --- A: QK sub0 (pure MFMA) ---
    __builtin_amdgcn_s_setprio(1);
#pragma unroll
    for (int c = 0; c < 2; ++c)
#pragma unroll
      for (int t = 0; t < 4; ++t) {
        bf16x8 ak = *(const bf16x8*)(&K0[(16 * t + l15) * 64 + (((4 * c + quad) ^ swz) * 8)]);
#pragma unroll
        for (int m = 0; m < 4; ++m)
          s0[m][t] = __builtin_amdgcn_mfma_f32_16x16x32_bf16(ak, qf[m][c], s0[m][t], 0, 0, 0);
      }
    __builtin_amdgcn_s_setprio(0);

    // --- B: QK sub1 interleaved with softmax(sub0) ---
#pragma unroll
    for (int u = 0; u < 4; ++u) {
      // 8 MFMAs of QK1 (t-slice u)
#pragma unroll
      for (int c = 0; c < 2; ++c) {
        bf16x8 ak = *(const bf16x8*)(&K1[(16 * u + l15) * 64 + (((4 * c + quad) ^ swz) * 8)]);
#pragma unroll
        for (int m = 0; m < 4; ++m)
          s1[m][u] = __builtin_amdgcn_mfma_f32_16x16x32_bf16(ak, qf[m][c], s1[m][u], 0, 0, 0);
      }
      // 16 exp2 + pack of SM0 (m-slice u)
#pragma unroll
      for (int t = 0; t < 4; ++t)
#pragma unroll
        for (int r = 0; r < 4; ++r)
          s0[u][t][r] = fast_exp2(s0[u][t][r]);
#pragma unroll
      for (int c2 = 0; c2 < 2; ++c2) {
        bf16x8 a;
#pragma unroll
        for (int r = 0; r < 4; ++r) {
          a[r]     = (__bf16)s0[u][2 * c2][r];
          a[4 + r] = (__bf16)s0[u][2 * c2 + 1][r];
        }
        p0[u][c2] = a;
      }
    }

    // --- C: PV sub0 interleaved with softmax(sub1), + ones0 ---
#pragma unroll
    for (int u = 0; u < 4; ++u) {
      // 8 MFMAs of PV0 (t-slice u)
#pragma unroll
      for (int c2 = 0; c2 < 2; ++c2) {
        bf16x8 bv = *(const bf16x8*)(&V0[(16 * u + l15) * 64 + (((4 * c2 + quad) ^ swz) * 8)]);
#pragma unroll
        for (int m = 0; m < 4; ++m)
          acco[m][u] = __builtin_amdgcn_mfma_f32_16x16x32_bf16(p0[m][c2], bv, acco[m][u], 0, 0, 0);
      }
      // 16 exp2 + pack of SM1 (m-slice u)
#pragma unroll
      for (int t = 0; t < 4; ++t)
#pragma unroll
        for (int r = 0; r < 4; ++r)
          s1[u][t][r] = fast_exp2(s1[u][t][r]);
#pragma unroll
      for (int c2 = 0; c2 < 2; ++c2) {
        bf16x8 a;
#pragma unroll
        for (int r = 0; r < 4; ++r) {
          a[r]     = (__bf16)s1[u][2 * c2][r];
          a[4 + r] = (__bf16)s1[u][2 * c2 + 1][r];
        }
        p1[u][c2] = a;
      }
    }
#pragma unroll
    for (int c2 = 0; c2 < 2; ++c2)
#pragma unroll
      for (int m = 0; m < 4; ++m)
        lacc[m] = __builtin_amdgcn_mfma_f32_16x16x32_bf16(p0[m][c2], onesb, lacc[m], 0, 0, 0);

    // --- D: PV sub1 + ones1 (pure MFMA) ---
    __builtin_amdgcn_s_setprio(1);
#pragma unroll
    for (int u = 0; u < 4; ++u)
#pragma unroll
      for (int c2 = 0; c2 < 2; ++c2) {
        bf16x8 bv = *(const bf16x8*)(&V1[(16 * u + l15) * 64 + (((4 * c2 + quad) ^ swz) * 8)]);
#pragma unroll
        for (int m = 0; m < 4; ++m)
          acco[m][u] = __builtin_amdgcn_mfma_f32_16x16x32_bf16(p1[m][c2], bv, acco[m][u], 0, 0, 0);
      }
#pragma unroll
    for (int c2 = 0; c2 < 2; ++c2)
#pragma unroll
      for (int m = 0; m < 4; ++m)
        lacc[m] = __builtin_amdgcn_mfma_f32_16x16x32_bf16(p1[m][c2], onesb, lacc[m], 0, 0, 0);
    __builtin_amdgcn_s_setprio(0);
  };

  // --- 2-stage pipeline: 1 barrier per 128-row buffer (2 tiles); DMA issued
  // a full 2-tile compute phase before its vmcnt(0) drain at the next
  // barrier. 16 buffer-fills cover the 2048-row z-half. ---
  dma_tile(0);
  for (int it = 0; it < 16; it += 2) {
    __syncthreads();                      // buf0 resident; buf1 reads done
    dma_tile(1);
    compute_pair(0);
    __syncthreads();                      // buf1 resident; buf0 reads done
    if (it < 14) dma_tile(0);
    compute_pair(1);
  }

  // epilogue: row sums (lacc cols all identical; rows = 4*quad+r) +
  // unnormalized partial O
#pragma unroll
  for (int m = 0; m < 4; ++m) {
    if (l15 == 0) {
#pragma unroll
      for (int r = 0; r < 4; ++r)
        lws[z * 65536 + bh * 4096 + iw + 16 * m + 4 * quad + r] = lacc[m][r];
    }
  }
  if (z == 0) {
    __bf16* Ob = OP0 + (size_t)bh * 262144;
#pragma unroll
    for (int m = 0; m < 4; ++m)
#pragma unroll
      for (int t = 0; t < 4; ++t)
#pragma unroll
        for (int r = 0; r < 4; ++r)
          Ob[(size_t)(iw + 16 * m + 4 * quad + r) * 64 + 16 * t + l15] =
              (__bf16)acco[m][t][r];
  } else {
    float* Ob = Og + (size_t)bh * 262144;
#pragma unroll
    for (int m = 0; m < 4; ++m)
#pragma unroll
      for (int t = 0; t < 4; ++t)
#pragma unroll
        for (int r = 0; r < 4; ++r)
          Ob[(size_t)(iw + 16 * m + 4 * quad + r) * 64 + 16 * t + l15] =
              acco[m][t][r];
  }
}

// ---------------------------------------------------------------------------
// Kernel 4: combine halves: out = (O1 + O0) / (l0 + l1). Og holds O1 (f32).
// ---------------------------------------------------------------------------
__global__ __launch_bounds__(256) void combine(
    const __bf16* __restrict__ OP0, const float* __restrict__ lws,
    float* __restrict__ Og)
{
  int idx = blockIdx.x * 256 + threadIdx.x;
  int row = idx >> 4;
  float inv = 1.0f / (lws[row] + lws[65536 + row]);
  f32x4 o = ((const f32x4*)Og)[idx];
  bf16x4 p = ((const bf16x4*)OP0)[idx];
  f32x4 r;
#pragma unroll
  for (int k = 0; k < 4; ++k) r[k] = (o[k] + (float)p[k]) * inv;
  ((f32x4*)Og)[idx] = r;
}

// ---------------------------------------------------------------------------
extern "C" void kernel_launch(void* const* d_in, const int* in_sizes, int n_in,
                              void* d_out, int out_size, void* d_ws, size_t ws_size,
                              hipStream_t stream) {
  const float* fmap = (const float*)d_in[0];
  const float* w    = (const float*)d_in[1];
  const float* ph   = (const float*)d_in[2];
  const float* pw   = (const float*)d_in[3];
  float* out = (float*)d_out;

  __bf16* Qw = (__bf16*)d_ws;            // 4*256*4096 elems each (8 MiB)
  __bf16* Kw = Qw + 4194304;
  __bf16* Vw = Kw + 4194304;             // dead after v_transpose -> OP0 alias
  __bf16* Vt = Vw + 4194304;
  float*  lws = (float*)(Vt + 4194304);  // 2*65536 f32 (512 KiB)
  __bf16* Wb16 = (__bf16*)(lws + 131072);// 768*256 bf16 (384 KiB)

  w_cvt      <<<dim3(192),       256, 0, stream>>>(w, Wb16);
  qkv_proj   <<<dim3(128, 4),    256, 0, stream>>>(fmap, Wb16, ph, pw, Qw, Kw, Vw);
  v_transpose<<<dim3(64, 16),    256, 0, stream>>>(Vw, Vt);
  flash_attn <<<dim3(16, 16, 2), 256, 0, stream>>>(Qw, Kw, Vt, Vw /*OP0*/, lws, out);
  combine    <<<dim3(4096),      256, 0, stream>>>(Vw /*OP0*/, lws, out);
}

// Round 4
// 180.715 us; speedup vs baseline: 1.0259x; 1.0259x over previous
//
#include <hip/hip_runtime.h>

// BoTNet attention, MI355X bf16-MFMA, round 11.
//  * raw .view: (b,o,s) row-major == (bh,i,d) row-major -> no relayout.
//  * pos bias folded into K; log2(e) folded into Q scale (exp2 softmax).
//  * S^T trick + pi-permuted K staging: softmaxed accumulators packed to bf16
//    ARE the PV A-fragments. pi: pr = (r&0x23)|((r&0x0C)<<1)|((r&0x10)>>2).
//  * R9: BK=128/buffer, ones-B MFMA row sums, setprio. 78->69us.
//  * R10: 4-phase cross-sub-tile interleave (A=QK0 | B=QK1+SM0 | C=PV0+SM1 |
//    D=PV1). NULL: compiler re-clumped MFMA/VALU clusters (MfmaUtil 44, dur
//    73us) -- source order didn't survive list scheduling.
//  * R11: sched_group_barrier pins the B/C interleave: per u-slice
//    [2 DS_READ, 8 x (1 MFMA, 3 VALU)] so exp2/pack issue in the matrix-pipe
//    accept gaps. Phases A/D stay pure-MFMA under setprio(1).
// ws: Q | K' | V(->OP0 alias) | V^T (8 MiB each) | l[2][65536] f32 | Wb16.

typedef float  f32x4  __attribute__((ext_vector_type(4)));
typedef __bf16 bf16x8 __attribute__((ext_vector_type(8)));
typedef __bf16 bf16x4 __attribute__((ext_vector_type(4)));

__device__ inline float fast_exp2(float x) {
#if __has_builtin(__builtin_amdgcn_exp2f)
  return __builtin_amdgcn_exp2f(x);
#else
  return exp2f(x);
#endif
}

__device__ inline void glds16(const __bf16* g, __bf16* l) {
  __builtin_amdgcn_global_load_lds(
      (const __attribute__((address_space(1))) void*)g,
      (__attribute__((address_space(3))) void*)l, 16, 0, 0);
}

// ---------------------------------------------------------------------------
// Kernel 0: W f32 -> bf16.
// ---------------------------------------------------------------------------
__global__ __launch_bounds__(256) void w_cvt(
    const float* __restrict__ w, __bf16* __restrict__ wb)
{
  int idx = blockIdx.x * 256 + threadIdx.x;
  f32x4 v = ((const f32x4*)w)[idx];
  bf16x4 o; o[0]=(__bf16)v[0]; o[1]=(__bf16)v[1]; o[2]=(__bf16)v[2]; o[3]=(__bf16)v[3];
  ((bf16x4*)wb)[idx] = o;
}

// ---------------------------------------------------------------------------
// Kernel 1: qkv projection v2 (unchanged).
// ---------------------------------------------------------------------------
__global__ __launch_bounds__(256) void qkv_proj(
    const float* __restrict__ fmap, const __bf16* __restrict__ wb,
    const float* __restrict__ ph,   const float* __restrict__ pw,
    __bf16* __restrict__ Qw, __bf16* __restrict__ Kw, __bf16* __restrict__ Vw)
{
  constexpr int LS = 264;
  __shared__ __bf16 Bs[32 * LS];
  const int tid  = threadIdx.x;
  const int wv   = tid >> 6;
  const int lane = tid & 63;
  const int quad = lane >> 4, l15 = lane & 15;
  const int n0 = blockIdx.x * 32;
  const int b  = blockIdx.y;

#pragma unroll
  for (int i = 0; i < 2; ++i) {
    int id = tid + i * 256;
    int ng = id & 7;
    int kg = id >> 3;
    const float* base = fmap + ((size_t)b * 256 + 4 * kg) * 4096 + n0 + 4 * ng;
    f32x4 v0 = *(const f32x4*)(base);
    f32x4 v1 = *(const f32x4*)(base + 4096);
    f32x4 v2 = *(const f32x4*)(base + 8192);
    f32x4 v3 = *(const f32x4*)(base + 12288);
#pragma unroll
    for (int j = 0; j < 4; ++j) {
      bf16x4 o; o[0]=(__bf16)v0[j]; o[1]=(__bf16)v1[j]; o[2]=(__bf16)v2[j]; o[3]=(__bf16)v3[j];
      *(bf16x4*)(&Bs[(4 * ng + j) * LS + 4 * kg]) = o;
    }
  }
  __syncthreads();

  for (int mt = 0; mt < 12; ++mt) {
    const int region = mt >> 2;
    const int obase  = (mt & 3) * 64;
    const __bf16* aptr = wb + (size_t)(mt * 64 + 16 * wv + l15) * 256 + 8 * quad;

    f32x4 acc[2] = {};
#pragma unroll
    for (int k0 = 0; k0 < 256; k0 += 32) {
      bf16x8 af = *(const bf16x8*)(aptr + k0);
      bf16x8 b0 = *(const bf16x8*)(&Bs[(l15)      * LS + k0 + 8 * quad]);
      bf16x8 b1 = *(const bf16x8*)(&Bs[(16 + l15) * LS + k0 + 8 * quad]);
      acc[0] = __builtin_amdgcn_mfma_f32_16x16x32_bf16(af, b0, acc[0], 0, 0, 0);
      acc[1] = __builtin_amdgcn_mfma_f32_16x16x32_bf16(af, b1, acc[1], 0, 0, 0);
    }

#pragma unroll
    for (int t = 0; t < 2; ++t) {
#pragma unroll
      for (int rr = 0; rr < 4; ++rr) {
        int oreg = obase + 16 * wv + 4 * quad + rr;
        int s    = n0 + 16 * t + l15;
        float val = acc[t][rr];
        size_t off = ((size_t)(b * 256 + oreg)) * 4096 + s;
        if (region == 0) {
          Qw[off] = (__bf16)(val * 0.18033688f);      // 0.125 * log2(e)
        } else if (region == 1) {
          int g = oreg & 63;
          float bias = ph[g * 64 + (s & 63)] + pw[(s >> 6) * 64 + (s & 63)];
          Kw[off] = (__bf16)(val + bias);
        } else {
          Vw[off] = (__bf16)val;
        }
      }
    }
  }
}

// ---------------------------------------------------------------------------
// Kernel 2: V transpose per (b,h): (4096 j x 64 d) -> (64 d x 4096 j)
// ---------------------------------------------------------------------------
__global__ __launch_bounds__(256) void v_transpose(
    const __bf16* __restrict__ Vw, __bf16* __restrict__ Vt)
{
  __shared__ __bf16 T[64 * 72];
  const int tid = threadIdx.x;
  const int j0  = blockIdx.x * 64;
  const int bh  = blockIdx.y;
  const __bf16* src = Vw + (size_t)bh * 262144;
#pragma unroll
  for (int i = 0; i < 2; ++i) {
    int id = tid + i * 256;
    int r = id >> 3, c = (id & 7) * 8;
    *(bf16x8*)(&T[r * 72 + c]) = *(const bf16x8*)(src + (size_t)(j0 + r) * 64 + c);
  }
  __syncthreads();
#pragma unroll
  for (int i = 0; i < 2; ++i) {
    int id = tid + i * 256;
    int d = id >> 3, jc = (id & 7) * 8;
    bf16x8 o;
#pragma unroll
    for (int z = 0; z < 8; ++z) o[z] = T[(jc + z) * 72 + d];
    *(bf16x8*)(Vt + ((size_t)bh * 64 + d) * 4096 + j0 + jc) = o;
  }
}

// ---------------------------------------------------------------------------
// Kernel 3: flash attention v11. m=4 (64 Q-rows/wave, 256/block), BK=128 per
// LDS buffer, 4-phase cross-sub-tile interleave pinned by
// sched_group_barrier, KV-split over z, 2-stage DMA pipeline with
// double-buffered LDS. grid (16, 16, 2), block 256.
// ---------------------------------------------------------------------------
__global__ __launch_bounds__(256, 2) void flash_attn(
    const __bf16* __restrict__ Qg, const __bf16* __restrict__ Kg,
    const __bf16* __restrict__ Vtg, __bf16* __restrict__ OP0,
    float* __restrict__ lws, float* __restrict__ Og)
{
  __shared__ __bf16 Ks[2 * 128 * 64];     // double-buffered 128-row tiles
  __shared__ __bf16 Vs[2 * 128 * 64];     // (64 KiB total LDS)
  const int tid  = threadIdx.x;
  const int wv   = tid >> 6;
  const int lane = tid & 63;
  const int quad = lane >> 4, l15 = lane & 15;
  const int bh = blockIdx.y;
  const int z  = blockIdx.z;
  const int iw = blockIdx.x * 256 + 64 * wv;
  const int jbase = z * 2048;
  const __bf16* Qb = Qg  + (size_t)bh * 262144;
  const __bf16* Kb = Kg  + (size_t)bh * 262144;
  const __bf16* Vb = Vtg + (size_t)bh * 262144;

  // Q B-frags in registers
  bf16x8 qf[4][2];
#pragma unroll
  for (int m = 0; m < 4; ++m)
#pragma unroll
    for (int c = 0; c < 2; ++c)
      qf[m][c] = *(const bf16x8*)(Qb + (size_t)(iw + 16 * m + l15) * 64 + 32 * c + 8 * quad);

  // DMA staging descriptors (source-side xor swizzle, pi-permuted K rows)
  const int r0  = tid >> 3;
  const int kch = tid & 7;
  const int xc  = (kch ^ (r0 & 7)) * 8;
  const int pr0a = r0, pr1a = r0 + 32;
  const int pr0 = (pr0a & 0x23) | ((pr0a & 0x0C) << 1) | ((pr0a & 0x10) >> 2);
  const int pr1 = (pr1a & 0x23) | ((pr1a & 0x0C) << 1) | ((pr1a & 0x10) >> 2);
  const __bf16* kp0 = Kb + (size_t)(jbase + pr0) * 64 + xc;
  const __bf16* kp1 = Kb + (size_t)(jbase + pr1) * 64 + xc;
  const __bf16* vp0 = Vb + (size_t)r0 * 4096        + jbase + xc;
  const __bf16* vp1 = Vb + (size_t)(r0 + 32) * 4096 + jbase + xc;

  f32x4 acco[4][4] = {};
  f32x4 lacc[4] = {};                     // row sums via ones-B MFMA
  const int swz = (l15 & 7);

  bf16x8 onesb;
#pragma unroll
  for (int r = 0; r < 8; ++r) onesb[r] = (__bf16)1.0f;

  // --- pipeline helpers (buf = 0/1 LDS halves, 8192 elems apart; each buf
  // holds two 64-row sub-tiles 4096 elems apart) ---
  auto dma_tile = [&](int buf) {
    __bf16* k0 = &Ks[buf * 8192 + tid * 8];
    __bf16* v0 = &Vs[buf * 8192 + tid * 8];
    glds16(kp0, k0);         kp0 += 4096;   // sub0: +64 K rows
    glds16(kp1, k0 + 2048);  kp1 += 4096;
    glds16(vp0, v0);         vp0 += 64;     // sub0: +64 V^T cols
    glds16(vp1, v0 + 2048);  vp1 += 64;
    glds16(kp0, k0 + 4096);  kp0 += 4096;   // sub1
    glds16(kp1, k0 + 6144);  kp1 += 4096;
    glds16(vp0, v0 + 4096);  vp0 += 64;
    glds16(vp1, v0 + 6144);  vp1 += 64;
  };

  // sched_group_barrier pattern for one interleaved u-slice:
  // [2 x DS_READ, 8 x (1 MFMA, 3 VALU)]  (VALU slots absorb exp2 + cvt/pack)
  auto sgb_slice = [&]() {
    __builtin_amdgcn_sched_group_barrier(0x100, 2, 0);   // DS_READ
#pragma unroll
    for (int g = 0; g < 8; ++g) {
      __builtin_amdgcn_sched_group_barrier(0x008, 1, 0); // MFMA
      __builtin_amdgcn_sched_group_barrier(0x002, 3, 0); // VALU (incl trans)
    }
  };

  // 4-phase pair: A=QK0 | B=QK1 (+)SM0 | C=PV0+ones0 (+)SM1 | D=PV1+ones1.
  auto compute_pair = [&](int buf) {
    const __bf16* K0 = &Ks[buf * 8192];
    const __bf16* K1 = K0 + 4096;
    const __bf16* V0 = &Vs[buf * 8192];
    const __bf16* V1 = V0 + 4096;
    f32x4 s0[4][4] = {};
    f32x4 s1[4][4] = {};
    bf16x8 p0[4][2], p1[4][2];

    // --- A: QK sub0 (pure MFMA) ---
    __builtin_amdgcn_s_setprio(1);
#pragma unroll
    for (int c = 0; c < 2; ++c)
#pragma unroll
      for (int t = 0; t < 4; ++t) {
        bf16x8 ak = *(const bf16x8*)(&K0[(16 * t + l15) * 64 + (((4 * c + quad) ^ swz) * 8)]);
#pragma unroll
        for (int m = 0; m < 4; ++m)
          s0[m][t] = __builtin_amdgcn_mfma_f32_16x16x32_bf16(ak, qf[m][c], s0[m][t], 0, 0, 0);
      }
    __builtin_amdgcn_s_setprio(0);

    // --- B: QK sub1 interleaved with softmax(sub0), SGB-pinned ---
#pragma unroll
    for (int u = 0; u < 4; ++u) {
      // 8 MFMAs of QK1 (t-slice u)
#pragma unroll
      for (int c = 0; c < 2; ++c) {
        bf16x8 ak = *(const bf16x8*)(&K1[(16 * u + l15) * 64 + (((4 * c + quad) ^ swz) * 8)]);
#pragma unroll
        for (int m = 0; m < 4; ++m)
          s1[m][u] = __builtin_amdgcn_mfma_f32_16x16x32_bf16(ak, qf[m][c], s1[m][u], 0, 0, 0);
      }
      // 16 exp2 + pack of SM0 (m-slice u)
#pragma unroll
      for (int t = 0; t < 4; ++t)
#pragma unroll
        for (int r = 0; r < 4; ++r)
          s0[u][t][r] = fast_exp2(s0[u][t][r]);
#pragma unroll
      for (int c2 = 0; c2 < 2; ++c2) {
        bf16x8 a;
#pragma unroll
        for (int r = 0; r < 4; ++r) {
          a[r]     = (__bf16)s0[u][2 * c2][r];
          a[4 + r] = (__bf16)s0[u][2 * c2 + 1][r];
        }
        p0[u][c2] = a;
      }
      sgb_slice();
    }

    // --- C: PV sub0 interleaved with softmax(sub1), + ones0, SGB-pinned ---
#pragma unroll
    for (int u = 0; u < 4; ++u) {
      // 8 MFMAs of PV0 (t-slice u)
#pragma unroll
      for (int c2 = 0; c2 < 2; ++c2) {
        bf16x8 bv = *(const bf16x8*)(&V0[(16 * u + l15) * 64 + (((4 * c2 + quad) ^ swz) * 8)]);
#pragma unroll
        for (int m = 0; m < 4; ++m)
          acco[m][u] = __builtin_amdgcn_mfma_f32_16x16x32_bf16(p0[m][c2], bv, acco[m][u], 0, 0, 0);
      }
      // 16 exp2 + pack of SM1 (m-slice u)
#pragma unroll
      for (int t = 0; t < 4; ++t)
#pragma unroll
        for (int r = 0; r < 4; ++r)
          s1[u][t][r] = fast_exp2(s1[u][t][r]);
#pragma unroll
      for (int c2 = 0; c2 < 2; ++c2) {
        bf16x8 a;
#pragma unroll
        for (int r = 0; r < 4; ++r) {
          a[r]     = (__bf16)s1[u][2 * c2][r];
          a[4 + r] = (__bf16)s1[u][2 * c2 + 1][r];
        }
        p1[u][c2] = a;
      }
      sgb_slice();
    }
#pragma unroll
    for (int c2 = 0; c2 < 2; ++c2)
#pragma unroll
      for (int m = 0; m < 4; ++m)
        lacc[m] = __builtin_amdgcn_mfma_f32_16x16x32_bf16(p0[m][c2], onesb, lacc[m], 0, 0, 0);

    // --- D: PV sub1 + ones1 (pure MFMA) ---
    __builtin_amdgcn_s_setprio(1);
#pragma unroll
    for (int u = 0; u < 4; ++u)
#pragma unroll
      for (int c2 = 0; c2 < 2; ++c2) {
        bf16x8 bv = *(const bf16x8*)(&V1[(16 * u + l15) * 64 + (((4 * c2 + quad) ^ swz) * 8)]);
#pragma unroll
        for (int m = 0; m < 4; ++m)
          acco[m][u] = __builtin_amdgcn_mfma_f32_16x16x32_bf16(p1[m][c2], bv, acco[m][u], 0, 0, 0);
      }
#pragma unroll
    for (int c2 = 0; c2 < 2; ++c2)
#pragma unroll
      for (int m = 0; m < 4; ++m)
        lacc[m] = __builtin_amdgcn_mfma_f32_16x16x32_bf16(p1[m][c2], onesb, lacc[m], 0, 0, 0);
    __builtin_amdgcn_s_setprio(0);
  };

  // --- 2-stage pipeline: 1 barrier per 128-row buffer (2 tiles); DMA issued
  // a full 2-tile compute phase before its vmcnt(0) drain at the next
  // barrier. 16 buffer-fills cover the 2048-row z-half. ---
  dma_tile(0);
  for (int it = 0; it < 16; it += 2) {
    __syncthreads();                      // buf0 resident; buf1 reads done
    dma_tile(1);
    compute_pair(0);
    __syncthreads();                      // buf1 resident; buf0 reads done
    if (it < 14) dma_tile(0);
    compute_pair(1);
  }

  // epilogue: row sums (lacc cols all identical; rows = 4*quad+r) +
  // unnormalized partial O
#pragma unroll
  for (int m = 0; m < 4; ++m) {
    if (l15 == 0) {
#pragma unroll
      for (int r = 0; r < 4; ++r)
        lws[z * 65536 + bh * 4096 + iw + 16 * m + 4 * quad + r] = lacc[m][r];
    }
  }
  if (z == 0) {
    __bf16* Ob = OP0 + (size_t)bh * 262144;
#pragma unroll
    for (int m = 0; m < 4; ++m)
#pragma unroll
      for (int t = 0; t < 4; ++t)
#pragma unroll
        for (int r = 0; r < 4; ++r)
          Ob[(size_t)(iw + 16 * m + 4 * quad + r) * 64 + 16 * t + l15] =
              (__bf16)acco[m][t][r];
  } else {
    float* Ob = Og + (size_t)bh * 262144;
#pragma unroll
    for (int m = 0; m < 4; ++m)
#pragma unroll
      for (int t = 0; t < 4; ++t)
#pragma unroll
        for (int r = 0; r < 4; ++r)
          Ob[(size_t)(iw + 16 * m + 4 * quad + r) * 64 + 16 * t + l15] =
              acco[m][t][r];
  }
}

// ---------------------------------------------------------------------------
// Kernel 4: combine halves: out = (O1 + O0) / (l0 + l1). Og holds O1 (f32).
// ---------------------------------------------------------------------------
__global__ __launch_bounds__(256) void combine(
    const __bf16* __restrict__ OP0, const float* __restrict__ lws,
    float* __restrict__ Og)
{
  int idx = blockIdx.x * 256 + threadIdx.x;
  int row = idx >> 4;
  float inv = 1.0f / (lws[row] + lws[65536 + row]);
  f32x4 o = ((const f32x4*)Og)[idx];
  bf16x4 p = ((const bf16x4*)OP0)[idx];
  f32x4 r;
#pragma unroll
  for (int k = 0; k < 4; ++k) r[k] = (o[k] + (float)p[k]) * inv;
  ((f32x4*)Og)[idx] = r;
}

// ---------------------------------------------------------------------------
extern "C" void kernel_launch(void* const* d_in, const int* in_sizes, int n_in,
                              void* d_out, int out_size, void* d_ws, size_t ws_size,
                              hipStream_t stream) {
  const float* fmap = (const float*)d_in[0];
  const float* w    = (const float*)d_in[1];
  const float* ph   = (const float*)d_in[2];
  const float* pw   = (const float*)d_in[3];
  float* out = (float*)d_out;

  __bf16* Qw = (__bf16*)d_ws;            // 4*256*4096 elems each (8 MiB)
  __bf16* Kw = Qw + 4194304;
  __bf16* Vw = Kw + 4194304;             // dead after v_transpose -> OP0 alias
  __bf16* Vt = Vw + 4194304;
  float*  lws = (float*)(Vt + 4194304);  // 2*65536 f32 (512 KiB)
  __bf16* Wb16 = (__bf16*)(lws + 131072);// 768*256 bf16 (384 KiB)

  w_cvt      <<<dim3(192),       256, 0, stream>>>(w, Wb16);
  qkv_proj   <<<dim3(128, 4),    256, 0, stream>>>(fmap, Wb16, ph, pw, Qw, Kw, Vw);
  v_transpose<<<dim3(64, 16),    256, 0, stream>>>(Vw, Vt);
  flash_attn <<<dim3(16, 16, 2), 256, 0, stream>>>(Qw, Kw, Vt, Vw /*OP0*/, lws, out);
  combine    <<<dim3(4096),      256, 0, stream>>>(Vw /*OP0*/, lws, out);
}

// Round 5
// 170.686 us; speedup vs baseline: 1.0862x; 1.0588x over previous
//
#include <hip/hip_runtime.h>

// BoTNet attention, MI355X bf16-MFMA, round 12.
//  * raw .view: (b,o,s) row-major == (bh,i,d) row-major -> no relayout.
//  * pos bias folded into K; log2(e) folded into Q scale (exp2 softmax).
//  * S^T trick + pi-permuted K staging: softmaxed accumulators packed to bf16
//    ARE the PV A-fragments. pi: pr = (r&0x23)|((r&0x0C)<<1)|((r&0x10)>>2).
//  * R9: BK=128/buffer, ones-B MFMA row sums, setprio. flash 78->69us.
//  * R10/R11 (REVERTED): MFMA/VALU interleave by source order & by
//    sched_group_barrier both null (exp2 is TRANS-class; scheduler clumps).
//  * R12: in-block KV-split kills the combine pipeline. 512-thr blocks,
//    8 waves: waves 0-3 do kv[0,2048), waves 4-7 kv[2048,4096) for the same
//    256 Q rows. Epilogue exchanges partials through dead K/V LDS and writes
//    final f32 out directly. Deletes combine kernel + OP0/Og/lws traffic
//    (~200 MB HBM, ~30us) and one launch. LDS 128 KiB, 1 block/CU,
//    8 waves/CU (same wave count as R9). Flash inner loop = R9 verbatim.
// ws: Q | K' | V | V^T (8 MiB each) | Wb16.

typedef float  f32x4  __attribute__((ext_vector_type(4)));
typedef __bf16 bf16x8 __attribute__((ext_vector_type(8)));
typedef __bf16 bf16x4 __attribute__((ext_vector_type(4)));

__device__ inline float fast_exp2(float x) {
#if __has_builtin(__builtin_amdgcn_exp2f)
  return __builtin_amdgcn_exp2f(x);
#else
  return exp2f(x);
#endif
}

__device__ inline void glds16(const __bf16* g, __bf16* l) {
  __builtin_amdgcn_global_load_lds(
      (const __attribute__((address_space(1))) void*)g,
      (__attribute__((address_space(3))) void*)l, 16, 0, 0);
}

// ---------------------------------------------------------------------------
// Kernel 0: W f32 -> bf16.
// ---------------------------------------------------------------------------
__global__ __launch_bounds__(256) void w_cvt(
    const float* __restrict__ w, __bf16* __restrict__ wb)
{
  int idx = blockIdx.x * 256 + threadIdx.x;
  f32x4 v = ((const f32x4*)w)[idx];
  bf16x4 o; o[0]=(__bf16)v[0]; o[1]=(__bf16)v[1]; o[2]=(__bf16)v[2]; o[3]=(__bf16)v[3];
  ((bf16x4*)wb)[idx] = o;
}

// ---------------------------------------------------------------------------
// Kernel 1: qkv projection v2 (unchanged).
// ---------------------------------------------------------------------------
__global__ __launch_bounds__(256) void qkv_proj(
    const float* __restrict__ fmap, const __bf16* __restrict__ wb,
    const float* __restrict__ ph,   const float* __restrict__ pw,
    __bf16* __restrict__ Qw, __bf16* __restrict__ Kw, __bf16* __restrict__ Vw)
{
  constexpr int LS = 264;
  __shared__ __bf16 Bs[32 * LS];
  const int tid  = threadIdx.x;
  const int wv   = tid >> 6;
  const int lane = tid & 63;
  const int quad = lane >> 4, l15 = lane & 15;
  const int n0 = blockIdx.x * 32;
  const int b  = blockIdx.y;

#pragma unroll
  for (int i = 0; i < 2; ++i) {
    int id = tid + i * 256;
    int ng = id & 7;
    int kg = id >> 3;
    const float* base = fmap + ((size_t)b * 256 + 4 * kg) * 4096 + n0 + 4 * ng;
    f32x4 v0 = *(const f32x4*)(base);
    f32x4 v1 = *(const f32x4*)(base + 4096);
    f32x4 v2 = *(const f32x4*)(base + 8192);
    f32x4 v3 = *(const f32x4*)(base + 12288);
#pragma unroll
    for (int j = 0; j < 4; ++j) {
      bf16x4 o; o[0]=(__bf16)v0[j]; o[1]=(__bf16)v1[j]; o[2]=(__bf16)v2[j]; o[3]=(__bf16)v3[j];
      *(bf16x4*)(&Bs[(4 * ng + j) * LS + 4 * kg]) = o;
    }
  }
  __syncthreads();

  for (int mt = 0; mt < 12; ++mt) {
    const int region = mt >> 2;
    const int obase  = (mt & 3) * 64;
    const __bf16* aptr = wb + (size_t)(mt * 64 + 16 * wv + l15) * 256 + 8 * quad;

    f32x4 acc[2] = {};
#pragma unroll
    for (int k0 = 0; k0 < 256; k0 += 32) {
      bf16x8 af = *(const bf16x8*)(aptr + k0);
      bf16x8 b0 = *(const bf16x8*)(&Bs[(l15)      * LS + k0 + 8 * quad]);
      bf16x8 b1 = *(const bf16x8*)(&Bs[(16 + l15) * LS + k0 + 8 * quad]);
      acc[0] = __builtin_amdgcn_mfma_f32_16x16x32_bf16(af, b0, acc[0], 0, 0, 0);
      acc[1] = __builtin_amdgcn_mfma_f32_16x16x32_bf16(af, b1, acc[1], 0, 0, 0);
    }

#pragma unroll
    for (int t = 0; t < 2; ++t) {
#pragma unroll
      for (int rr = 0; rr < 4; ++rr) {
        int oreg = obase + 16 * wv + 4 * quad + rr;
        int s    = n0 + 16 * t + l15;
        float val = acc[t][rr];
        size_t off = ((size_t)(b * 256 + oreg)) * 4096 + s;
        if (region == 0) {
          Qw[off] = (__bf16)(val * 0.18033688f);      // 0.125 * log2(e)
        } else if (region == 1) {
          int g = oreg & 63;
          float bias = ph[g * 64 + (s & 63)] + pw[(s >> 6) * 64 + (s & 63)];
          Kw[off] = (__bf16)(val + bias);
        } else {
          Vw[off] = (__bf16)val;
        }
      }
    }
  }
}

// ---------------------------------------------------------------------------
// Kernel 2: V transpose per (b,h): (4096 j x 64 d) -> (64 d x 4096 j)
// ---------------------------------------------------------------------------
__global__ __launch_bounds__(256) void v_transpose(
    const __bf16* __restrict__ Vw, __bf16* __restrict__ Vt)
{
  __shared__ __bf16 T[64 * 72];
  const int tid = threadIdx.x;
  const int j0  = blockIdx.x * 64;
  const int bh  = blockIdx.y;
  const __bf16* src = Vw + (size_t)bh * 262144;
#pragma unroll
  for (int i = 0; i < 2; ++i) {
    int id = tid + i * 256;
    int r = id >> 3, c = (id & 7) * 8;
    *(bf16x8*)(&T[r * 72 + c]) = *(const bf16x8*)(src + (size_t)(j0 + r) * 64 + c);
  }
  __syncthreads();
#pragma unroll
  for (int i = 0; i < 2; ++i) {
    int id = tid + i * 256;
    int d = id >> 3, jc = (id & 7) * 8;
    bf16x8 o;
#pragma unroll
    for (int z = 0; z < 8; ++z) o[z] = T[(jc + z) * 72 + d];
    *(bf16x8*)(Vt + ((size_t)bh * 64 + d) * 4096 + j0 + jc) = o;
  }
}

// ---------------------------------------------------------------------------
// Kernel 3: flash attention v12. 512 threads = 8 waves; waves 0-3 handle
// kv [0,2048), waves 4-7 kv [2048,4096) for the same 256 Q rows. m=4 per
// wave, BK=128 per LDS buffer (R9 inner loop), 2-stage DMA pipeline,
// in-LDS partial combine + direct f32 out. grid (16,16), block 512.
// ---------------------------------------------------------------------------
__global__ __launch_bounds__(512, 2) void flash_attn(
    const __bf16* __restrict__ Qg, const __bf16* __restrict__ Kg,
    const __bf16* __restrict__ Vtg, float* __restrict__ out)
{
  // 128 KiB: K tiles [z][buf][4096] then V tiles [z][buf][4096].
  __shared__ __align__(16) __bf16 SMEM[65536];
  __bf16* Ks = SMEM;                      // 32768 elems (64 KiB)
  __bf16* Vs = SMEM + 32768;              // 32768 elems (64 KiB)

  const int tid  = threadIdx.x;
  const int wv   = tid >> 6;
  const int lane = tid & 63;
  const int quad = lane >> 4, l15 = lane & 15;
  const int zi   = wv >> 2;               // kv half this wave computes
  const int wl   = wv & 3;                // q-slot within the half
  const int bh = blockIdx.y;
  const int iw = blockIdx.x * 256 + 64 * wl;
  const __bf16* Qb = Qg  + (size_t)bh * 262144;
  const __bf16* Kb = Kg  + (size_t)bh * 262144;
  const __bf16* Vb = Vtg + (size_t)bh * 262144;

  // Q B-frags in registers
  bf16x8 qf[4][2];
#pragma unroll
  for (int m = 0; m < 4; ++m)
#pragma unroll
    for (int c = 0; c < 2; ++c)
      qf[m][c] = *(const bf16x8*)(Qb + (size_t)(iw + 16 * m + l15) * 64 + 32 * c + 8 * quad);

  // DMA staging (all 512 threads stage BOTH kv halves).
  // r0 in [0,64): one glds16 round covers a full 64-row sub-tile.
  const int r0  = tid >> 3;
  const int kch = tid & 7;
  const int xc  = (kch ^ (r0 & 7)) * 8;
  const int prr = (r0 & 0x23) | ((r0 & 0x0C) << 1) | ((r0 & 0x10) >> 2);
  const __bf16* kp0 = Kb + (size_t)prr * 64 + xc;             // kv half 0
  const __bf16* kp1 = Kb + (size_t)(2048 + prr) * 64 + xc;    // kv half 1
  const __bf16* vp0 = Vb + (size_t)r0 * 4096 + xc;
  const __bf16* vp1 = Vb + (size_t)r0 * 4096 + 2048 + xc;

  f32x4 acco[4][4] = {};
  f32x4 lacc[4] = {};                     // row sums via ones-B MFMA
  const int swz = (l15 & 7);

  bf16x8 onesb;
#pragma unroll
  for (int r = 0; r < 8; ++r) onesb[r] = (__bf16)1.0f;

  // --- staging: per buffer, 8 glds16/thread fill K/V for both halves
  // (two 64-row sub-tiles each). ---
  auto dma_tile = [&](int buf) {
    __bf16* kd0 = &Ks[buf * 8192 + tid * 8];            // z=0
    __bf16* kd1 = &Ks[16384 + buf * 8192 + tid * 8];    // z=1
    __bf16* vd0 = &Vs[buf * 8192 + tid * 8];
    __bf16* vd1 = &Vs[16384 + buf * 8192 + tid * 8];
    glds16(kp0, kd0);         kp0 += 4096;   // sub0 (+64 K rows)
    glds16(kp0, kd0 + 4096);  kp0 += 4096;   // sub1
    glds16(kp1, kd1);         kp1 += 4096;
    glds16(kp1, kd1 + 4096);  kp1 += 4096;
    glds16(vp0, vd0);         vp0 += 64;     // sub0 (+64 V^T cols)
    glds16(vp0, vd0 + 4096);  vp0 += 64;     // sub1
    glds16(vp1, vd1);         vp1 += 64;
    glds16(vp1, vd1 + 4096);  vp1 += 64;
  };

  auto compute_tile = [&](int buf, int sub) {
    const __bf16* Kbuf = &Ks[zi * 16384 + buf * 8192 + sub * 4096];
    const __bf16* Vbuf = &Vs[zi * 16384 + buf * 8192 + sub * 4096];
    // S^T = mfma(K-slot rows, Q rows)
    f32x4 sacc[4][4] = {};
    __builtin_amdgcn_s_setprio(1);
#pragma unroll
    for (int c = 0; c < 2; ++c) {
#pragma unroll
      for (int t = 0; t < 4; ++t) {
        bf16x8 ak = *(const bf16x8*)(&Kbuf[(16 * t + l15) * 64 + (((4 * c + quad) ^ swz) * 8)]);
#pragma unroll
        for (int m = 0; m < 4; ++m)
          sacc[m][t] = __builtin_amdgcn_mfma_f32_16x16x32_bf16(ak, qf[m][c], sacc[m][t], 0, 0, 0);
      }
    }
    __builtin_amdgcn_s_setprio(0);
    // softmax numerator + pack PV A-frags (identity via pi)
    bf16x8 pf[4][2];
#pragma unroll
    for (int m = 0; m < 4; ++m) {
#pragma unroll
      for (int t = 0; t < 4; ++t)
#pragma unroll
        for (int r = 0; r < 4; ++r)
          sacc[m][t][r] = fast_exp2(sacc[m][t][r]);
#pragma unroll
      for (int c2 = 0; c2 < 2; ++c2) {
        bf16x8 a;
#pragma unroll
        for (int r = 0; r < 4; ++r) {
          a[r]     = (__bf16)sacc[m][2 * c2][r];
          a[4 + r] = (__bf16)sacc[m][2 * c2 + 1][r];
        }
        pf[m][c2] = a;
      }
    }
    // O += P . V ; l += P . 1 (ones-B MFMA row sums, all 16 cols identical)
    __builtin_amdgcn_s_setprio(1);
#pragma unroll
    for (int c2 = 0; c2 < 2; ++c2) {
#pragma unroll
      for (int t = 0; t < 4; ++t) {
        bf16x8 bv = *(const bf16x8*)(&Vbuf[(16 * t + l15) * 64 + (((4 * c2 + quad) ^ swz) * 8)]);
#pragma unroll
        for (int m = 0; m < 4; ++m)
          acco[m][t] = __builtin_amdgcn_mfma_f32_16x16x32_bf16(pf[m][c2], bv, acco[m][t], 0, 0, 0);
      }
#pragma unroll
      for (int m = 0; m < 4; ++m)
        lacc[m] = __builtin_amdgcn_mfma_f32_16x16x32_bf16(pf[m][c2], onesb, lacc[m], 0, 0, 0);
    }
    __builtin_amdgcn_s_setprio(0);
  };

  // --- 2-stage pipeline: 1 barrier per 128-row buffer (2 sub-tiles); DMA
  // issued a full compute phase before its vmcnt(0) drain at the next
  // barrier. 16 buffer fills cover each 2048-row kv half. ---
  dma_tile(0);
  for (int it = 0; it < 16; it += 2) {
    __syncthreads();                      // buf0 resident; buf1 reads done
    dma_tile(1);
    compute_tile(0, 0);
    compute_tile(0, 1);
    __syncthreads();                      // buf1 resident; buf0 reads done
    if (it < 14) dma_tile(0);
    compute_tile(1, 0);
    compute_tile(1, 1);
  }

  // --- epilogue: in-LDS partial combine, normalized f32 out. ---
  __syncthreads();                        // K/V tiles dead; reuse as f32 X
  float* X = (float*)SMEM;                // 256 slots x 84 f32 (86 KiB)
  const int slot = (wl * 64 + lane) * 84;
  if (zi == 1) {
#pragma unroll
    for (int m = 0; m < 4; ++m) {
#pragma unroll
      for (int t = 0; t < 4; ++t)
        *(f32x4*)(&X[slot + m * 16 + t * 4]) = acco[m][t];
      *(f32x4*)(&X[slot + 64 + m * 4]) = lacc[m];
    }
  }
  __syncthreads();
  if (zi == 0) {
    float* Ob = out + (size_t)bh * 262144;
#pragma unroll
    for (int m = 0; m < 4; ++m) {
      f32x4 l1 = *(const f32x4*)(&X[slot + 64 + m * 4]);
      f32x4 lt = lacc[m] + l1;
      f32x4 inv;
#pragma unroll
      for (int r = 0; r < 4; ++r) inv[r] = 1.0f / lt[r];
#pragma unroll
      for (int t = 0; t < 4; ++t) {
        f32x4 o1 = *(const f32x4*)(&X[slot + m * 16 + t * 4]);
        f32x4 ot = acco[m][t] + o1;
#pragma unroll
        for (int r = 0; r < 4; ++r)
          Ob[(size_t)(iw + 16 * m + 4 * quad + r) * 64 + 16 * t + l15] =
              ot[r] * inv[r];
      }
    }
  }
}

// ---------------------------------------------------------------------------
extern "C" void kernel_launch(void* const* d_in, const int* in_sizes, int n_in,
                              void* d_out, int out_size, void* d_ws, size_t ws_size,
                              hipStream_t stream) {
  const float* fmap = (const float*)d_in[0];
  const float* w    = (const float*)d_in[1];
  const float* ph   = (const float*)d_in[2];
  const float* pw   = (const float*)d_in[3];
  float* out = (float*)d_out;

  __bf16* Qw = (__bf16*)d_ws;            // 4*256*4096 elems each (8 MiB)
  __bf16* Kw = Qw + 4194304;
  __bf16* Vw = Kw + 4194304;
  __bf16* Vt = Vw + 4194304;
  __bf16* Wb16 = Vt + 4194304;           // 768*256 bf16 (384 KiB)

  w_cvt      <<<dim3(192),    256, 0, stream>>>(w, Wb16);
  qkv_proj   <<<dim3(128, 4), 256, 0, stream>>>(fmap, Wb16, ph, pw, Qw, Kw, Vw);
  v_transpose<<<dim3(64, 16), 256, 0, stream>>>(Vw, Vt);
  flash_attn <<<dim3(16, 16), 512, 0, stream>>>(Qw, Kw, Vt, out);
}